// Round 6
// baseline (526.009 us; speedup 1.0000x reference)
//
#include <hip/hip_runtime.h>

#define NN 50000
#define NE 400000
#define NBATCH 16
#define DH 128
#define DE 64
#define DHID 256
#define BP 136   // node-kernel h-tile LDS pitch (bf16): 128 + 8
#define SCP 258  // Sc LDS row pitch (bf16): 256 + 2

typedef __attribute__((ext_vector_type(8))) short bf16x8;
typedef __attribute__((ext_vector_type(4))) float f32x4;

__device__ __forceinline__ unsigned enc_f(float f) {
  unsigned u = __float_as_uint(f);
  return (u & 0x80000000u) ? ~u : (u | 0x80000000u);
}
__device__ __forceinline__ float dec_f(unsigned x) {
  unsigned u = (x & 0x80000000u) ? (x ^ 0x80000000u) : ~x;
  return __uint_as_float(u);
}
__device__ __forceinline__ unsigned f2bf(float x) {
  unsigned u = __float_as_uint(x);
  return (u + 0x7fffu + ((u >> 16) & 1u)) >> 16;
}
__device__ __forceinline__ void bf8_unpack(uint4 v, float* f) {
  f[0] = __uint_as_float(v.x << 16); f[1] = __uint_as_float(v.x & 0xffff0000u);
  f[2] = __uint_as_float(v.y << 16); f[3] = __uint_as_float(v.y & 0xffff0000u);
  f[4] = __uint_as_float(v.z << 16); f[5] = __uint_as_float(v.z & 0xffff0000u);
  f[6] = __uint_as_float(v.w << 16); f[7] = __uint_as_float(v.w & 0xffff0000u);
}
__device__ __forceinline__ bf16x8 pack_bf8(float4 a, float4 b) {
  union { bf16x8 v; unsigned u[4]; } r;
  r.u[0] = f2bf(a.x) | (f2bf(a.y) << 16);
  r.u[1] = f2bf(a.z) | (f2bf(a.w) << 16);
  r.u[2] = f2bf(b.x) | (f2bf(b.y) << 16);
  r.u[3] = f2bf(b.z) | (f2bf(b.w) << 16);
  return r.v;
}

__global__ void init_seg(unsigned* __restrict__ segmax, float* __restrict__ segsum) {
  int i = blockIdx.x * 256 + threadIdx.x;
  if (i < NN) { segmax[i] = 0u; segsum[i] = 0.0f; }
}

// Fragment-major weight layouts (A-operand of mfma_f32_16x16x32_bf16):
// WbS: frag f=((sec*16+T)*4+ki), element [f*64 + lane]*8 + j =
//      W[(koff + ki*32 + (lane>>4)*8 + j)][hid = T*16 + (lane&15)]
//      sec0=W1g[0:128](gate-src) sec1=W1s[0:128](score-src)
//      sec2=W1g[128:256](gate-dst) sec3=W1s[128:256](score-dst)
// Wbe: frag f=(t*2+ki): [f*64+lane]*8+j = W1s[256 + ki*32 + (lane>>4)*8 + j][t*16 + (lane&15)]
__global__ void w2bf(const float* __restrict__ W1g, const float* __restrict__ W1s,
                     unsigned short* __restrict__ WbS, unsigned short* __restrict__ Wbe) {
  int idx = blockIdx.x * 256 + threadIdx.x;   // 147456 total
  if (idx < 131072) {
    int j = idx & 7, lane = (idx >> 3) & 63, ki = (idx >> 9) & 3;
    int T = (idx >> 11) & 15, sec = idx >> 15;
    int m = lane & 15, kg = lane >> 4;
    int hid = T * 16 + m;
    int k = ki * 32 + kg * 8 + j;
    const float* W = (sec & 1) ? W1s : W1g;
    int koff = (sec >> 1) * 128;
    WbS[idx] = (unsigned short)f2bf(W[(koff + k) * DHID + hid]);
  } else {
    int i = idx - 131072;                     // 16384
    int j = i & 7, lane = (i >> 3) & 63, ki = (i >> 9) & 1, t = i >> 10;
    int m = lane & 15, kg = lane >> 4;
    int hid = t * 16 + m;
    int k = ki * 32 + kg * 8 + j;
    Wbe[i] = (unsigned short)f2bf(W1s[(2 * DH + k) * DHID + hid]);
  }
}

// Zq permuted fp32: Zq[b*256 + slot], slot = q*64 + t*4 + r, hid = 16t+4q+r.
__global__ void zq_kernel(const float* __restrict__ q, const float* __restrict__ W1g,
                          const float* __restrict__ b1g, float* __restrict__ Zq) {
  int b = blockIdx.x, c = threadIdx.x;   // c = hid
  float acc = b1g[c];
#pragma unroll 4
  for (int k = 0; k < DH; ++k)
    acc = fmaf(q[b * DH + k], W1g[(2 * DH + k) * DHID + c], acc);
  int t = c >> 4, qq = (c >> 2) & 3, r = c & 3;
  Zq[b * 256 + qq * 64 + t * 4 + r] = acc;
}

// Node projections: block = 128 nodes, ALL 1024 hid rows. h staged once to
// LDS (bf16); B-frags preloaded to registers; A-frags streamed from
// fragment-major WbS (L2-resident) with no LDS and no inner barriers.
// P: per node 1024 bf16 = 4 sections x 256 slots; slot = q*64 + T*4 + r.
__global__ __launch_bounds__(256, 2)
void node_gemm(const float* __restrict__ h, const unsigned short* __restrict__ WbS,
               unsigned short* __restrict__ P) {
  __shared__ unsigned short Bs[128 * BP];   // 34816 B
  const int tid = threadIdx.x;
  const int lane = tid & 63, wave = tid >> 6;
  const int node0 = blockIdx.x * 128;

  // stage h rows node0..+127, fp32 -> bf16
#pragma unroll
  for (int it = 0; it < 16; ++it) {
    int fi = it * 256 + tid;            // 4096 float4 = 128 rows x 32
    int row = fi >> 5, f4 = fi & 31;
    int n = node0 + row;
    float4 v = make_float4(0.f, 0.f, 0.f, 0.f);
    if (n < NN) v = *(const float4*)&h[(size_t)n * DH + f4 * 4];
    uint2 pk = make_uint2(f2bf(v.x) | (f2bf(v.y) << 16),
                          f2bf(v.z) | (f2bf(v.w) << 16));
    *(uint2*)(Bs + row * BP + f4 * 4) = pk;
  }
  __syncthreads();

  const int r15 = lane & 15, q = lane >> 4;
  // preload all B fragments into registers (32 x bf16x8 = 128 VGPR)
  bf16x8 b[8][4];
#pragma unroll
  for (int nj = 0; nj < 8; ++nj)
#pragma unroll
    for (int ki = 0; ki < 4; ++ki)
      b[nj][ki] = *(const bf16x8*)(Bs + (nj * 16 + r15) * BP + ki * 32 + q * 8);

  const bf16x8* AF = (const bf16x8*)WbS;
  // mt -> (sec = mt&3, T = wave*4 + (mt>>2))
  bf16x8 a[4], an[4];
#pragma unroll
  for (int ki = 0; ki < 4; ++ki)
    a[ki] = AF[(((0 & 3) * 16 + wave * 4 + 0) * 4 + ki) * 64 + lane];

  for (int mt = 0; mt < 16; ++mt) {
    if (mt < 15) {
      int sec = (mt + 1) & 3, T = wave * 4 + ((mt + 1) >> 2);
#pragma unroll
      for (int ki = 0; ki < 4; ++ki)
        an[ki] = AF[((sec * 16 + T) * 4 + ki) * 64 + lane];
    }
    f32x4 acc[8];
#pragma unroll
    for (int nj = 0; nj < 8; ++nj) acc[nj] = (f32x4)(0.f);
#pragma unroll
    for (int ki = 0; ki < 4; ++ki)
#pragma unroll
      for (int nj = 0; nj < 8; ++nj)
        acc[nj] = __builtin_amdgcn_mfma_f32_16x16x32_bf16(a[ki], b[nj][ki], acc[nj], 0, 0, 0);
    const int sec = mt & 3, T = wave * 4 + (mt >> 2);
#pragma unroll
    for (int nj = 0; nj < 8; ++nj) {
      int node = node0 + nj * 16 + r15;
      if (node < NN) {
        f32x4 v = acc[nj];
        uint2 pk = make_uint2(f2bf(v.x) | (f2bf(v.y) << 16),
                              f2bf(v.z) | (f2bf(v.w) << 16));
        *(uint2*)(P + (size_t)node * 1024 + sec * 256 + q * 64 + T * 4) = pk;
      }
    }
#pragma unroll
    for (int ki = 0; ki < 4; ++ki) a[ki] = an[ki];
  }
}

// Fused edge kernel: MFMA e-GEMM (A-frags from L2 frag-major Wbe, B-frags
// direct from eattr) -> Sc LDS round-trip -> coalesced gather epilogue.
__global__ __launch_bounds__(256)
void edge_kernel(const float* __restrict__ eattr, const int* __restrict__ eidx,
                 const int* __restrict__ ebat, const unsigned short* __restrict__ Wbe,
                 const float* __restrict__ b1s,
                 const float* __restrict__ W2g, const float* __restrict__ b2g,
                 const float* __restrict__ W2s, const float* __restrict__ b2s,
                 const unsigned short* __restrict__ P, const float* __restrict__ Zq,
                 float* __restrict__ raw, unsigned* __restrict__ segmax) {
  __shared__ unsigned short Sc[64 * SCP];   // 33024 B
  __shared__ float w2g_s[256], w2s_s[256], b1s_s[256];  // slot-permuted
  __shared__ int src_s[64], dst_s[64], bat_s[64];
  const int tid = threadIdx.x;
  const int lane = tid & 63, wave = tid >> 6;
  const int e0 = blockIdx.x * 64;

  {
    int c = tid;                           // slot -> hid = 16t + 4q + r
    int qq = c >> 6, t = (c >> 2) & 15, r = c & 3;
    int hid = t * 16 + qq * 4 + r;
    w2g_s[c] = W2g[hid];
    w2s_s[c] = W2s[hid];
    b1s_s[c] = b1s[hid];
  }
  if (tid < 64) {
    src_s[tid] = eidx[e0 + tid];
    dst_s[tid] = eidx[NE + e0 + tid];
    bat_s[tid] = ebat[e0 + tid];
  }

  const int r15 = lane & 15, q = lane >> 4;
  const int eloc = wave * 16 + r15;
  // B fragments straight from eattr (each lane: 8 consecutive k of its edge)
  const float* erow = eattr + (size_t)(e0 + eloc) * DE;
  bf16x8 eb0, eb1;
  {
    float4 v0 = *(const float4*)(erow + q * 8);
    float4 v1 = *(const float4*)(erow + q * 8 + 4);
    float4 v2 = *(const float4*)(erow + 32 + q * 8);
    float4 v3 = *(const float4*)(erow + 32 + q * 8 + 4);
    eb0 = pack_bf8(v0, v1);
    eb1 = pack_bf8(v2, v3);
  }

  const bf16x8* AF = (const bf16x8*)Wbe;   // frag idx = t*128 + ki*64 + lane
  f32x4 acc[16];
#pragma unroll
  for (int t = 0; t < 16; ++t) acc[t] = (f32x4)(0.f);
  bf16x8 a0 = AF[lane], a1 = AF[64 + lane];
#pragma unroll
  for (int t = 0; t < 16; ++t) {
    bf16x8 c0 = a0, c1 = a1;
    if (t < 15) {
      a0 = AF[(t + 1) * 128 + lane];
      a1 = AF[(t + 1) * 128 + 64 + lane];
    }
    acc[t] = __builtin_amdgcn_mfma_f32_16x16x32_bf16(c0, eb0, acc[t], 0, 0, 0);
    acc[t] = __builtin_amdgcn_mfma_f32_16x16x32_bf16(c1, eb1, acc[t], 0, 0, 0);
  }

  // dump Sc to LDS (slot order per edge row)
#pragma unroll
  for (int t = 0; t < 16; ++t) {
    f32x4 v = acc[t];
    uint2 pk = make_uint2(f2bf(v.x) | (f2bf(v.y) << 16),
                          f2bf(v.z) | (f2bf(v.w) << 16));
    *(uint2*)(Sc + eloc * SCP + q * 64 + t * 4) = pk;
  }
  __syncthreads();

  // ---- coalesced gather epilogue: 2 edges/wave/round, 8 rounds ----
  const uint4* Pq = (const uint4*)P;   // node row = 128 uint4
  const int cx = lane & 31, eh = lane >> 5;
  const float b2gv = b2g[0], b2sv = b2s[0];
  const int so = cx * 8;
  float4 wg0 = *(const float4*)&w2g_s[so], wg1 = *(const float4*)&w2g_s[so + 4];
  float4 ws0 = *(const float4*)&w2s_s[so], ws1 = *(const float4*)&w2s_s[so + 4];
  float4 bs0 = *(const float4*)&b1s_s[so], bs1 = *(const float4*)&b1s_s[so + 4];
  const float wg[8] = {wg0.x, wg0.y, wg0.z, wg0.w, wg1.x, wg1.y, wg1.z, wg1.w};
  const float wsv[8] = {ws0.x, ws0.y, ws0.z, ws0.w, ws1.x, ws1.y, ws1.z, ws1.w};
  const float bsv[8] = {bs0.x, bs0.y, bs0.z, bs0.w, bs1.x, bs1.y, bs1.z, bs1.w};

  int er = wave * 16 + eh;
  int s = src_s[er], d = dst_s[er], b = bat_s[er];
  uint4 gi_n = Pq[(size_t)s * 128 + cx];
  uint4 ss_n = Pq[(size_t)s * 128 + 32 + cx];
  uint4 gj_n = Pq[(size_t)d * 128 + 64 + cx];
  uint4 sd_n = Pq[(size_t)d * 128 + 96 + cx];

  for (int rr = 0; rr < 8; ++rr) {
    uint4 gi = gi_n, ss = ss_n, gj = gj_n, sd = sd_n;
    const int ercur = er, dcur = d, bcur = b;
    if (rr < 7) {
      er = wave * 16 + (rr + 1) * 2 + eh;
      s = src_s[er]; d = dst_s[er]; b = bat_s[er];
      gi_n = Pq[(size_t)s * 128 + cx];
      ss_n = Pq[(size_t)s * 128 + 32 + cx];
      gj_n = Pq[(size_t)d * 128 + 64 + cx];
      sd_n = Pq[(size_t)d * 128 + 96 + cx];
    }
    uint4 sc = *(const uint4*)(Sc + ercur * SCP + so);
    float4 z0 = *(const float4*)&Zq[bcur * 256 + so];
    float4 z1 = *(const float4*)&Zq[bcur * 256 + so + 4];
    float gif[8], gjf[8], ssf[8], sdf[8], scf[8];
    bf8_unpack(gi, gif); bf8_unpack(gj, gjf);
    bf8_unpack(ss, ssf); bf8_unpack(sd, sdf);
    bf8_unpack(sc, scf);
    const float zq[8] = {z0.x, z0.y, z0.z, z0.w, z1.x, z1.y, z1.z, z1.w};
    float gp = 0.f, sp = 0.f;
#pragma unroll
    for (int i = 0; i < 8; ++i) {
      gp = fmaf(fmaxf(gif[i] + gjf[i] + zq[i], 0.f), wg[i], gp);
      sp = fmaf(fmaxf(scf[i] + ssf[i] + sdf[i] + bsv[i], 0.f), wsv[i], sp);
    }
#pragma unroll
    for (int m = 16; m >= 1; m >>= 1) {
      gp += __shfl_xor(gp, m);
      sp += __shfl_xor(sp, m);
    }
    if (cx == 0) {
      float gate = 1.f / (1.f + __expf(-(gp + b2gv)));
      float rv = gate * (sp + b2sv);
      raw[e0 + ercur] = rv;
      atomicMax(&segmax[dcur], enc_f(rv));
    }
  }
}

__global__ void exp_pass(const float* __restrict__ raw, const int* __restrict__ dstp,
                         const unsigned* __restrict__ segmax, float* __restrict__ out,
                         float* __restrict__ segsum) {
  int i = blockIdx.x * 256 + threadIdx.x;
  if (i < NE) {
    int d = dstp[i];
    float ex = __expf(raw[i] - dec_f(segmax[d]));
    out[i] = ex;
    atomicAdd(&segsum[d], ex);
  }
}

__global__ void norm_pass(float* __restrict__ out, const int* __restrict__ dstp,
                          const float* __restrict__ segsum) {
  int i = blockIdx.x * 256 + threadIdx.x;
  if (i < NE) out[i] = out[i] / fmaxf(segsum[dstp[i]], 1e-9f);
}

extern "C" void kernel_launch(void* const* d_in, const int* in_sizes, int n_in,
                              void* d_out, int out_size, void* d_ws, size_t ws_size,
                              hipStream_t stream) {
  const float* h   = (const float*)d_in[0];
  const float* e   = (const float*)d_in[1];
  const float* q   = (const float*)d_in[2];
  const int* eidx  = (const int*)d_in[3];
  const int* ebat  = (const int*)d_in[4];
  const float* W1g = (const float*)d_in[5];
  const float* b1g = (const float*)d_in[6];
  const float* W2g = (const float*)d_in[7];
  const float* b2g = (const float*)d_in[8];
  const float* W1s = (const float*)d_in[9];
  const float* b1s = (const float*)d_in[10];
  const float* W2s = (const float*)d_in[11];
  const float* b2s = (const float*)d_in[12];
  float* out = (float*)d_out;

  // ws carve: P(bf16 102.4MB) | Zq | raw | segmax | segsum | WbS | Wbe
  unsigned short* P = (unsigned short*)d_ws;
  float* Zq = (float*)(P + (size_t)NN * 1024);
  float* raw = Zq + NBATCH * DHID;
  unsigned* segmax = (unsigned*)(raw + NE);
  float* segsum = (float*)(segmax + NN);
  unsigned short* WbS = (unsigned short*)(segsum + NN);
  unsigned short* Wbe = WbS + 131072;

  hipLaunchKernelGGL(init_seg, dim3(196), dim3(256), 0, stream, segmax, segsum);
  hipLaunchKernelGGL(w2bf, dim3(576), dim3(256), 0, stream, W1g, W1s, WbS, Wbe);
  hipLaunchKernelGGL(zq_kernel, dim3(NBATCH), dim3(256), 0, stream, q, W1g, b1g, Zq);
  hipLaunchKernelGGL(node_gemm, dim3(391), dim3(256), 0, stream, h, WbS, P);
  hipLaunchKernelGGL(edge_kernel, dim3(NE / 64), dim3(256), 0, stream,
                     e, eidx, ebat, Wbe, b1s, W2g, b2g, W2s, b2s, P, Zq, raw, segmax);
  hipLaunchKernelGGL(exp_pass, dim3(1563), dim3(256), 0, stream,
                     raw, eidx + NE, segmax, out, segsum);
  hipLaunchKernelGGL(norm_pass, dim3(1563), dim3(256), 0, stream,
                     out, eidx + NE, segsum);
}